// Round 18
// baseline (592.839 us; speedup 1.0000x reference)
//
#include <hip/hip_runtime.h>

#define B_SZ 8192
#define IN_SZ 1024
#define G_SZ 100
#define F_SZ 128

using f32x4 = __attribute__((ext_vector_type(4))) float;
using s16x8 = __attribute__((ext_vector_type(8))) short;
typedef __bf16 bf16x8 __attribute__((ext_vector_type(8)));

__device__ __forceinline__ short cvt_bf16(float f) {      // HW RNE f32->bf16
    __bf16 h = (__bf16)f;
    return __builtin_bit_cast(short, h);
}
__device__ __forceinline__ float bfs2f(short s) {
    union { unsigned u; float f; } v; v.u = ((unsigned)(unsigned short)s) << 16;
    return v.f;
}

// async global->LDS, 16B per lane; LDS dest = uniform base + lane*16
#define GLDS(gp, lp) __builtin_amdgcn_global_load_lds( \
    (const __attribute__((address_space(1))) void*)(gp), \
    (__attribute__((address_space(3))) void*)(lp), 16, 0, 0)

// ---------------------------------------------------------------------------
// Gather: Ag[g][b][f] = bf16(x[b][uf[g*128+f]])
// ---------------------------------------------------------------------------
__global__ __launch_bounds__(256) void k_gather(const float* __restrict__ x,
                                                const int* __restrict__ uf,
                                                unsigned short* __restrict__ Ag) {
    __shared__ __align__(16) unsigned short xrow[16][1032];
    const int t = threadIdx.x;
    const int b0 = blockIdx.x * 16;
    #pragma unroll
    for (int i = 0; i < 16; ++i) {
        int c4 = t + i * 256;
        int r = c4 >> 8;
        int cc = (c4 & 255) << 2;
        float4 v = *reinterpret_cast<const float4*>(&x[(size_t)(b0 + r) * IN_SZ + cc]);
        ushort4 o;
        o.x = (unsigned short)cvt_bf16(v.x); o.y = (unsigned short)cvt_bf16(v.y);
        o.z = (unsigned short)cvt_bf16(v.z); o.w = (unsigned short)cvt_bf16(v.w);
        *reinterpret_cast<ushort4*>(&xrow[r][cc]) = o;
    }
    __syncthreads();
    for (int i = 0; i < 200; ++i) {
        int c = t + i * 256;
        int ch = c & 31; int r = (c >> 5) & 15; int g = c >> 9;
        int4 id = *reinterpret_cast<const int4*>(&uf[g * F_SZ + ch * 4]);
        ushort4 o;
        o.x = xrow[r][id.x]; o.y = xrow[r][id.y]; o.z = xrow[r][id.z]; o.w = xrow[r][id.w];
        *reinterpret_cast<ushort4*>(&Ag[(((size_t)g * B_SZ + b0 + r) << 7) + ch * 4]) = o;
    }
}

// ---------------------------------------------------------------------------
// Pre-pack W (+bias at k==K_SRC when FOLD) into MFMA fragment order.
// ---------------------------------------------------------------------------
template<int K_SRC, int N_OUT, int NT, bool FOLD>
__device__ __forceinline__ void pack_one(int e, const float* __restrict__ W,
                                         const float* __restrict__ bias,
                                         unsigned short* __restrict__ P) {
    constexpr int EPG = 4 * NT * 64;
    int g = e / EPG; int r = e - g * EPG;
    int lane = r & 63; int nt = (r >> 6) % NT; int ks = r / (64 * NT);
    int n = nt * 16 + (lane & 15); int kb = ks * 32 + (lane >> 4) * 8;
    s16x8 v;
    #pragma unroll
    for (int j = 0; j < 8; ++j) {
        int k = kb + j; float val = 0.f;
        if (n < N_OUT) {
            if (k < K_SRC) val = W[((size_t)g * K_SRC + k) * N_OUT + n];
            else if (FOLD && k == K_SRC) val = bias[g * N_OUT + n];
        }
        v[j] = cvt_bf16(val);
    }
    *reinterpret_cast<s16x8*>(&P[(size_t)e * 8]) = v;
}

__global__ __launch_bounds__(256) void k_packW(
    const float* __restrict__ w0,
    const float* __restrict__ w1, const float* __restrict__ b1,
    const float* __restrict__ w2, const float* __restrict__ b2,
    unsigned short* __restrict__ p0, unsigned short* __restrict__ p1,
    unsigned short* __restrict__ p2) {
    int id = blockIdx.x * 256 + threadIdx.x;           // 460800 total
    if (id < 179200)       pack_one<128, 100, 7, false>(id, w0, nullptr, p0);
    else if (id < 358400)  pack_one<100, 100, 7, true >(id - 179200, w1, b1, p1);
    else                   pack_one<100,  50, 4, true >(id - 358400, w2, b2, p2);
}

// ---------------------------------------------------------------------------
// Per-group dense, bf16 MFMA 16x16x32, ONE 128-row tile per block.
//  REGISTER-MINIMAL variant targeting 5 waves/SIMD (unified VGPR+AGPR <=102):
//   - W staged in LDS from the packed table (28 linear global_load_lds,
//     zero-conflict ds_read_b128 at lane*16) -> zero W register pressure.
//   - A loaded PER-HALF inside each ks (8 live regs; halves sequential).
//   - Epilogue TRANSIENT: no rs/bvn arrays; bias loaded per-nt, stats
//     shfl->LDS-atomic immediately.
//  Footprint: acc 56 + a 8 + BN vecs ~16 + addr ~8 ~= 88-96 <= 102.
//  Evidence: dur = bytes/BW(waves) closes every round; at 5 waves & no
//  spill, 265MB/2.9TB/s ~= 92us/dense.  History: R16 (reg-W) and R17
//  (array epilogue) each landed 104 unified = 2 over -> partial spill.
//  Canary: WRITE ~165MB / FETCH ~95MB.
// ---------------------------------------------------------------------------
template<int K_SRC, int N_OUT, int NT, bool BN_IN, bool IS_LAST, bool HAS_BIAS>
__global__ __launch_bounds__(256, 5) void k_dense(
    const unsigned short* __restrict__ Ain,   // [G][B][K_SRC] bf16 row-major
    const unsigned short* __restrict__ Wf,    // [G][4*NT*64][8] packed
    const float* __restrict__ bias,           // only when HAS_BIAS
    const float* __restrict__ sa, const float* __restrict__ sb, // [G*128]
    unsigned short* __restrict__ Hout,        // [G][B][N_OUT] bf16
    float* __restrict__ pred,                 // [B][5000] f32
    float* __restrict__ ssum, float* __restrict__ ssq, // [G*100]
    const float* __restrict__ ow, float* __restrict__ out_acc)
{
    constexpr int EPG = 4 * NT * 64;
    constexpr int WBYTES = EPG * 16;               // 28672 (NT=7) / 16384 (NT=4)
    constexpr int UBYTES = WBYTES > 13312 ? WBYTES : 13312;
    __shared__ __align__(16) unsigned char U[UBYTES];
    __shared__ float ls1[IS_LAST ? 1 : NT * 16];
    __shared__ float ls2[IS_LAST ? 1 : NT * 16];

    const int t = threadIdx.x;
    const int g = blockIdx.x >> 6;
    const int m0 = (blockIdx.x & 63) << 7;
    const int lane = t & 63, wid = t >> 6;
    const int lr = lane & 15, lg = lane >> 4;

    if constexpr (!IS_LAST) {
        if (t < NT * 16) { ls1[t] = 0.f; ls2[t] = 0.f; }
    }

    // ---- stage W into LDS (linear, async, L2-hot source) ----
    constexpr int NCH = WBYTES / 1024;             // 28 / 16
    const char* wsrc = (const char*)(Wf + (size_t)g * EPG * 8);
    #pragma unroll
    for (int j = 0; j < (NCH + 3) / 4; ++j) {
        int i = j * 4 + wid;                       // wave-uniform chunk index
        if (i < NCH) GLDS(wsrc + i * 1024 + lane * 16, U + i * 1024);
    }
    __syncthreads();                               // drains vmcnt: W resident

    const unsigned short* Uw = (const unsigned short*)U;
    const unsigned short* r0 = Ain + ((size_t)g * B_SZ + m0 + wid * 32 + lr) * K_SRC;

    #define APP(vv, idx, s, o) { float f_ = bfs2f(vv[idx]) * (s) + (o); \
                                 vv[idx] = cvt_bf16(fmaxf(f_, 0.f)); }

    // ---- MFMA loop: A per-ks per-HALF (8 live regs), W from LDS ----
    f32x4 acc[2][NT] = {};
    #pragma unroll
    for (int ks = 0; ks < 4; ++ks) {
        const int kb = ks * 32 + lg * 8;
        #pragma unroll
        for (int h = 0; h < 2; ++h) {
            s16x8 a;
            if constexpr (K_SRC == 128) {
                a = *reinterpret_cast<const s16x8*>(r0 + h * 16 * 128 + kb);
            } else {  // K_SRC == 100
                if (ks < 3) {
                    reinterpret_cast<short4*>(&a)[0] =
                        *reinterpret_cast<const short4*>(r0 + h * 16 * 100 + kb);
                    reinterpret_cast<short4*>(&a)[1] =
                        *reinterpret_cast<const short4*>(r0 + h * 16 * 100 + kb + 4);
                } else {
                    a = s16x8{};
                    if (lg == 0)
                        reinterpret_cast<short4*>(&a)[0] =
                            *reinterpret_cast<const short4*>(r0 + h * 16 * 100 + 96);
                }
            }
            if constexpr (BN_IN) {
                if (ks < 3) {
                    float4 S0 = *reinterpret_cast<const float4*>(&sa[g * 128 + kb]);
                    float4 S1 = *reinterpret_cast<const float4*>(&sa[g * 128 + kb + 4]);
                    float4 O0 = *reinterpret_cast<const float4*>(&sb[g * 128 + kb]);
                    float4 O1 = *reinterpret_cast<const float4*>(&sb[g * 128 + kb + 4]);
                    APP(a,0,S0.x,O0.x) APP(a,1,S0.y,O0.y) APP(a,2,S0.z,O0.z) APP(a,3,S0.w,O0.w)
                    APP(a,4,S1.x,O1.x) APP(a,5,S1.y,O1.y) APP(a,6,S1.z,O1.z) APP(a,7,S1.w,O1.w)
                } else if (lg == 0) {   // tail channels 96..99 + bias slot 1.0
                    float4 S0 = *reinterpret_cast<const float4*>(&sa[g * 128 + 96]);
                    float4 O0 = *reinterpret_cast<const float4*>(&sb[g * 128 + 96]);
                    APP(a,0,S0.x,O0.x) APP(a,1,S0.y,O0.y) APP(a,2,S0.z,O0.z) APP(a,3,S0.w,O0.w)
                    a[4] = (short)0x3F80;
                }
            }
            bf16x8 av = __builtin_bit_cast(bf16x8, a);
            #pragma unroll
            for (int nt = 0; nt < NT; ++nt) {
                s16x8 b = *reinterpret_cast<const s16x8*>(Uw + (size_t)((ks * NT + nt) * 64 + lane) * 8);
                bf16x8 bv = __builtin_bit_cast(bf16x8, b);
                if constexpr (IS_LAST)
                    acc[h][nt] = __builtin_amdgcn_mfma_f32_16x16x32_bf16(bv, av, acc[h][nt], 0, 0, 0);
                else
                    acc[h][nt] = __builtin_amdgcn_mfma_f32_16x16x32_bf16(av, bv, acc[h][nt], 0, 0, 0);
            }
        }
    }
    #undef APP
    __syncthreads();                   // all W ds_reads done; U reusable

    // ---- epilogue: two 64-row phases, TRANSIENT stats (no arrays) ----
    if constexpr (!IS_LAST) {
        unsigned short* LH = (unsigned short*)U;
        #pragma unroll
        for (int p = 0; p < 2; ++p) {
            if ((wid >> 1) == p) {           // waves owning rows p*64..p*64+63
                #pragma unroll
                for (int nt = 0; nt < NT; ++nt) {
                    const int col = nt * 16 + lr;
                    const bool valid = col < N_OUT;
                    float bv = 0.f;
                    if constexpr (HAS_BIAS) bv = valid ? bias[g * N_OUT + col] : 0.f;
                    float s1 = 0.f, s2 = 0.f;
                    #pragma unroll
                    for (int mi = 0; mi < 2; ++mi) {
                        const int rloc = (wid & 1) * 32 + mi * 16 + (lg << 2);
                        #pragma unroll
                        for (int r = 0; r < 4; ++r) {
                            float v = acc[mi][nt][r] + bv;
                            short hb = cvt_bf16(v);
                            float vq = bfs2f(hb);
                            s1 += vq; s2 += vq * vq;
                            if (valid) LH[(rloc + r) * 104 + col] = (unsigned short)hb;
                        }
                    }
                    s1 += __shfl_xor(s1, 16); s1 += __shfl_xor(s1, 32);
                    s2 += __shfl_xor(s2, 16); s2 += __shfl_xor(s2, 32);
                    if (valid && lg == 0) {
                        atomicAdd(&ls1[col], s1);
                        atomicAdd(&ls2[col], s2);
                    }
                }
            }
            __syncthreads();                 // half-tile parked
            #pragma unroll
            for (int i = 0; i < 7; ++i) {
                int e = t + i * 256;
                if (e < 1600) {
                    int row = e / 25;
                    int c4 = (e - row * 25) * 4;
                    ushort4 v = *reinterpret_cast<const ushort4*>(&LH[row * 104 + c4]);
                    *reinterpret_cast<ushort4*>(
                        Hout + ((size_t)g * B_SZ + m0 + p * 64 + row) * 100 + c4) = v;
                }
            }
            __syncthreads();                 // LH reusable
        }
        if (t < N_OUT) {
            atomicAdd(&ssum[g * N_OUT + t], ls1[t]);
            atomicAdd(&ssq[g * N_OUT + t], ls2[t]);
        }
    } else {
        float* LP = (float*)U;
        #pragma unroll
        for (int p = 0; p < 2; ++p) {
            if ((wid >> 1) == p) {
                #pragma unroll
                for (int mi = 0; mi < 2; ++mi) {
                    const int bl = (wid & 1) * 32 + mi * 16 + lr;   // row in half
                    float dp = 0.f;
                    #pragma unroll
                    for (int nt = 0; nt < NT; ++nt) {
                        const int n0 = nt * 16 + (lg << 2);
                        f32x4 v = acc[mi][nt];
                        if (nt < 3) {
                            float2 w01 = *reinterpret_cast<const float2*>(&ow[g * N_OUT + n0]);
                            float2 w23 = *reinterpret_cast<const float2*>(&ow[g * N_OUT + n0 + 2]);
                            dp += v[0] * w01.x + v[1] * w01.y + v[2] * w23.x + v[3] * w23.y;
                            LP[bl * 52 + n0 + 0] = v[0]; LP[bl * 52 + n0 + 1] = v[1];
                            LP[bl * 52 + n0 + 2] = v[2]; LP[bl * 52 + n0 + 3] = v[3];
                        } else if (lg == 0) {  // n0 = 48: n=48,49 valid
                            float2 w01 = *reinterpret_cast<const float2*>(&ow[g * N_OUT + n0]);
                            dp += v[0] * w01.x + v[1] * w01.y;
                            LP[bl * 52 + n0 + 0] = v[0]; LP[bl * 52 + n0 + 1] = v[1];
                        }
                    }
                    dp += __shfl_xor(dp, 16); dp += __shfl_xor(dp, 32);
                    if (lg == 0) atomicAdd(&out_acc[m0 + p * 64 + bl], dp);
                }
            }
            __syncthreads();
            #pragma unroll
            for (int i = 0; i < 7; ++i) {
                int e = t + i * 256;
                if (e < 1600) {
                    int row = e / 25;
                    int c2 = e - row * 25;
                    float2 v = *reinterpret_cast<const float2*>(&LP[row * 52 + c2 * 2]);
                    *reinterpret_cast<float2*>(
                        &pred[(size_t)(m0 + p * 64 + row) * 5000 + g * N_OUT + c2 * 2]) = v;
                }
            }
            __syncthreads();
        }
    }
}

// BN finalize -> per-channel scale/offset (128-stride, identity pads).
__global__ __launch_bounds__(256) void k_bnfin(const float* __restrict__ ssum,
                                               const float* __restrict__ ssq,
                                               const float* __restrict__ gamma,
                                               const float* __restrict__ beta,
                                               float* __restrict__ sa,
                                               float* __restrict__ sb) {
    int c = blockIdx.x * 256 + threadIdx.x;
    if (c < G_SZ * 128) {
        int g = c >> 7, ch = c & 127;
        float s, o;
        if (ch < 100) {
            float mean = ssum[g * 100 + ch] * (1.f / 8192.f);
            float var = ssq[g * 100 + ch] * (1.f / 8192.f) - mean * mean;
            s = rsqrtf(var + 1e-5f) * gamma[g * 100 + ch];
            o = beta[g * 100 + ch] - mean * s;
        } else { s = 1.f; o = 0.f; }
        sa[c] = s; sb[c] = o;
    }
}

__global__ __launch_bounds__(256) void k_sig(const float* __restrict__ out_acc,
                                             const float* __restrict__ ob,
                                             float* __restrict__ out) {
    int b = blockIdx.x * 256 + threadIdx.x;
    if (b < B_SZ) {
        float v = ob[0] + out_acc[b];
        out[b] = 1.f / (1.f + expf(-v));
    }
}

extern "C" void kernel_launch(void* const* d_in, const int* in_sizes, int n_in,
                              void* d_out, int out_size, void* d_ws, size_t ws_size,
                              hipStream_t stream) {
    const float* x      = (const float*)d_in[0];
    const int*   uf     = (const int*)d_in[1];
    const float* w0     = (const float*)d_in[2];
    const float* b0     = (const float*)d_in[3];
    const float* w1     = (const float*)d_in[4];
    const float* b1     = (const float*)d_in[5];
    const float* w2     = (const float*)d_in[6];
    const float* b2     = (const float*)d_in[7];
    const float* gamma0 = (const float*)d_in[8];
    const float* beta0  = (const float*)d_in[9];
    const float* gamma1 = (const float*)d_in[10];
    const float* beta1  = (const float*)d_in[11];
    const float* ow     = (const float*)d_in[12];
    const float* ob     = (const float*)d_in[13];

    char* ws = (char*)d_ws;
    const size_t AG_BYTES = (size_t)G_SZ * B_SZ * 128 * 2;  // 209,715,200
    unsigned short* Ag = (unsigned short*)ws;
    unsigned short* h1 = Ag;   // row-major [100][8192][100] bf16; aliases Ag
    float* stat = (float*)(ws + AG_BYTES);
    float* sum0    = stat;            // 10000
    float* ssq0    = stat + 10000;
    float* sum1    = stat + 20000;
    float* ssq1    = stat + 30000;
    float* out_acc = stat + 40000;    // 8192  (zeroed region ends at 48192)
    float* sa0     = stat + 48192;    // 12800 each, fully written by bnfin
    float* sb0     = stat + 60992;
    float* sa1     = stat + 73792;
    float* sb1     = stat + 86592;    // ends 99392 floats = 397,568 B

    unsigned short* p0 = (unsigned short*)(ws + AG_BYTES + 397568);
    unsigned short* p1 = p0 + (size_t)179200 * 8;   // 2,867,200 B each
    unsigned short* p2 = p1 + (size_t)179200 * 8;   // p2: 1,638,400 B

    // h0 row-major in d_out's pred region (dead before dense2 writes pred).
    unsigned short* h0 = (unsigned short*)((float*)d_out + B_SZ);
    float* pred = (float*)d_out + B_SZ;
    float* sig  = (float*)d_out;

    hipMemsetAsync(stat, 0, 48192 * sizeof(float), stream);

    k_packW<<<1800, 256, 0, stream>>>(w0, w1, b1, w2, b2, p0, p1, p2);
    k_gather<<<B_SZ / 16, 256, 0, stream>>>(x, uf, Ag);

    // dense0: K=128 in, bias in epilogue
    k_dense<128, 100, 7, false, false, true><<<6400, 256, 0, stream>>>(
        Ag, p0, b0, nullptr, nullptr, h0, nullptr, sum0, ssq0, nullptr, nullptr);
    k_bnfin<<<50, 256, 0, stream>>>(sum0, ssq0, gamma0, beta0, sa0, sb0);

    // dense1: K=100 in (BN+fold), row-major out
    k_dense<100, 100, 7, true, false, false><<<6400, 256, 0, stream>>>(
        h0, p1, nullptr, sa0, sb0, h1, nullptr, sum1, ssq1, nullptr, nullptr);
    k_bnfin<<<50, 256, 0, stream>>>(sum1, ssq1, gamma1, beta1, sa1, sb1);

    // dense2: K=100 in (BN+fold), pred + dot out
    k_dense<100, 50, 4, true, true, false><<<6400, 256, 0, stream>>>(
        h1, p2, nullptr, sa1, sb1, nullptr, pred, nullptr, nullptr, ow, out_acc);

    k_sig<<<32, 256, 0, stream>>>(out_acc, ob, sig);
}

// Round 19
// 358.226 us; speedup vs baseline: 1.6549x; 1.6549x over previous
//
#include <hip/hip_runtime.h>

#define B_SZ 8192
#define IN_SZ 1024
#define G_SZ 100
#define F_SZ 128

using f32x4 = __attribute__((ext_vector_type(4))) float;
using s16x8 = __attribute__((ext_vector_type(8))) short;
typedef __bf16 bf16x8 __attribute__((ext_vector_type(8)));

__device__ __forceinline__ short cvt_bf16(float f) {      // HW RNE f32->bf16
    __bf16 h = (__bf16)f;
    return __builtin_bit_cast(short, h);
}
__device__ __forceinline__ float bfs2f(short s) {
    union { unsigned u; float f; } v; v.u = ((unsigned)(unsigned short)s) << 16;
    return v.f;
}

// async global->LDS, 16B per lane; LDS dest = uniform base + lane*16
#define GLDS(gp, lp) __builtin_amdgcn_global_load_lds( \
    (const __attribute__((address_space(1))) void*)(gp), \
    (__attribute__((address_space(3))) void*)(lp), 16, 0, 0)

// ---------------------------------------------------------------------------
// Gather: Ag[g][b][f] = bf16(x[b][uf[g*128+f]])
// ---------------------------------------------------------------------------
__global__ __launch_bounds__(256) void k_gather(const float* __restrict__ x,
                                                const int* __restrict__ uf,
                                                unsigned short* __restrict__ Ag) {
    __shared__ __align__(16) unsigned short xrow[16][1032];
    const int t = threadIdx.x;
    const int b0 = blockIdx.x * 16;
    #pragma unroll
    for (int i = 0; i < 16; ++i) {
        int c4 = t + i * 256;
        int r = c4 >> 8;
        int cc = (c4 & 255) << 2;
        float4 v = *reinterpret_cast<const float4*>(&x[(size_t)(b0 + r) * IN_SZ + cc]);
        ushort4 o;
        o.x = (unsigned short)cvt_bf16(v.x); o.y = (unsigned short)cvt_bf16(v.y);
        o.z = (unsigned short)cvt_bf16(v.z); o.w = (unsigned short)cvt_bf16(v.w);
        *reinterpret_cast<ushort4*>(&xrow[r][cc]) = o;
    }
    __syncthreads();
    for (int i = 0; i < 200; ++i) {
        int c = t + i * 256;
        int ch = c & 31; int r = (c >> 5) & 15; int g = c >> 9;
        int4 id = *reinterpret_cast<const int4*>(&uf[g * F_SZ + ch * 4]);
        ushort4 o;
        o.x = xrow[r][id.x]; o.y = xrow[r][id.y]; o.z = xrow[r][id.z]; o.w = xrow[r][id.w];
        *reinterpret_cast<ushort4*>(&Ag[(((size_t)g * B_SZ + b0 + r) << 7) + ch * 4]) = o;
    }
}

// ---------------------------------------------------------------------------
// Pre-pack W (+bias at k==K_SRC when FOLD) into MFMA fragment order.
// ---------------------------------------------------------------------------
template<int K_SRC, int N_OUT, int NT, bool FOLD>
__device__ __forceinline__ void pack_one(int e, const float* __restrict__ W,
                                         const float* __restrict__ bias,
                                         unsigned short* __restrict__ P) {
    constexpr int EPG = 4 * NT * 64;
    int g = e / EPG; int r = e - g * EPG;
    int lane = r & 63; int nt = (r >> 6) % NT; int ks = r / (64 * NT);
    int n = nt * 16 + (lane & 15); int kb = ks * 32 + (lane >> 4) * 8;
    s16x8 v;
    #pragma unroll
    for (int j = 0; j < 8; ++j) {
        int k = kb + j; float val = 0.f;
        if (n < N_OUT) {
            if (k < K_SRC) val = W[((size_t)g * K_SRC + k) * N_OUT + n];
            else if (FOLD && k == K_SRC) val = bias[g * N_OUT + n];
        }
        v[j] = cvt_bf16(val);
    }
    *reinterpret_cast<s16x8*>(&P[(size_t)e * 8]) = v;
}

__global__ __launch_bounds__(256) void k_packW(
    const float* __restrict__ w0,
    const float* __restrict__ w1, const float* __restrict__ b1,
    const float* __restrict__ w2, const float* __restrict__ b2,
    unsigned short* __restrict__ p0, unsigned short* __restrict__ p1,
    unsigned short* __restrict__ p2) {
    int id = blockIdx.x * 256 + threadIdx.x;           // 460800 total
    if (id < 179200)       pack_one<128, 100, 7, false>(id, w0, nullptr, p0);
    else if (id < 358400)  pack_one<100, 100, 7, true >(id - 179200, w1, b1, p1);
    else                   pack_one<100,  50, 4, true >(id - 358400, w2, b2, p2);
}

// ---------------------------------------------------------------------------
// Per-group dense, bf16 MFMA 16x16x32, ONE 128-row tile per block.
//  R17 structure at the NEVER-SPILLS occupancy tier:
//   - W staged in LDS from the packed table (28 linear global_load_lds,
//     zero-conflict ds_read_b128 at lane*16) -> no W register pressure,
//     no per-wave L2 latency chain.
//   - A loaded per-ks (16 live regs), BN fused at load.
//   - launch_bounds (256,4): unified footprint 104 <= 128 cap, 24 regs
//     headroom.  (256,5) is compiler-unreachable for this tile: R16/R17/R18
//     all spilled (2-8 regs over the ~96-102 effective cap), and spill at
//     5 waves floods the fabric (R18: 1.08GB/dispatch, 256us).
//  Canary: WRITE ~165MB / FETCH ~92MB = no spill.
// ---------------------------------------------------------------------------
template<int K_SRC, int N_OUT, int NT, bool BN_IN, bool IS_LAST, bool HAS_BIAS>
__global__ __launch_bounds__(256, 4) void k_dense(
    const unsigned short* __restrict__ Ain,   // [G][B][K_SRC] bf16 row-major
    const unsigned short* __restrict__ Wf,    // [G][4*NT*64][8] packed
    const float* __restrict__ bias,           // only when HAS_BIAS
    const float* __restrict__ sa, const float* __restrict__ sb, // [G*128]
    unsigned short* __restrict__ Hout,        // [G][B][N_OUT] bf16
    float* __restrict__ pred,                 // [B][5000] f32
    float* __restrict__ ssum, float* __restrict__ ssq, // [G*100]
    const float* __restrict__ ow, float* __restrict__ out_acc)
{
    constexpr int EPG = 4 * NT * 64;
    constexpr int WBYTES = EPG * 16;               // 28672 (NT=7) / 16384 (NT=4)
    constexpr int UBYTES = WBYTES > 13312 ? WBYTES : 13312;
    __shared__ __align__(16) unsigned char U[UBYTES];
    __shared__ float ls1[IS_LAST ? 1 : NT * 16];
    __shared__ float ls2[IS_LAST ? 1 : NT * 16];

    const int t = threadIdx.x;
    const int g = blockIdx.x >> 6;
    const int m0 = (blockIdx.x & 63) << 7;
    const int lane = t & 63, wid = t >> 6;
    const int lr = lane & 15, lg = lane >> 4;

    if constexpr (!IS_LAST) {
        if (t < NT * 16) { ls1[t] = 0.f; ls2[t] = 0.f; }
    }

    // ---- stage W into LDS (linear, async, L2-hot source) ----
    constexpr int NCH = WBYTES / 1024;             // 28 / 16
    const char* wsrc = (const char*)(Wf + (size_t)g * EPG * 8);
    #pragma unroll
    for (int j = 0; j < (NCH + 3) / 4; ++j) {
        int i = j * 4 + wid;                       // wave-uniform chunk index
        if (i < NCH) GLDS(wsrc + i * 1024 + lane * 16, U + i * 1024);
    }
    __syncthreads();                               // drains vmcnt: W resident

    const unsigned short* Uw = (const unsigned short*)U;
    const unsigned short* r0 = Ain + ((size_t)g * B_SZ + m0 + wid * 32 + lr) * K_SRC;

    #define APP(vv, idx, s, o) { float f_ = bfs2f(vv[idx]) * (s) + (o); \
                                 vv[idx] = cvt_bf16(fmaxf(f_, 0.f)); }

    // ---- MFMA loop: A per-ks from global (16 live regs), W from LDS ----
    f32x4 acc[2][NT] = {};
    #pragma unroll
    for (int ks = 0; ks < 4; ++ks) {
        s16x8 a0, a1;
        const int kb = ks * 32 + lg * 8;
        if constexpr (K_SRC == 128) {
            a0 = *reinterpret_cast<const s16x8*>(r0 + kb);
            a1 = *reinterpret_cast<const s16x8*>(r0 + 16 * 128 + kb);
        } else {  // K_SRC == 100
            if (ks < 3) {
                reinterpret_cast<short4*>(&a0)[0] = *reinterpret_cast<const short4*>(r0 + kb);
                reinterpret_cast<short4*>(&a0)[1] = *reinterpret_cast<const short4*>(r0 + kb + 4);
                reinterpret_cast<short4*>(&a1)[0] = *reinterpret_cast<const short4*>(r0 + 16 * 100 + kb);
                reinterpret_cast<short4*>(&a1)[1] = *reinterpret_cast<const short4*>(r0 + 16 * 100 + kb + 4);
            } else {
                a0 = s16x8{}; a1 = s16x8{};
                if (lg == 0) {
                    reinterpret_cast<short4*>(&a0)[0] = *reinterpret_cast<const short4*>(r0 + 96);
                    reinterpret_cast<short4*>(&a1)[0] = *reinterpret_cast<const short4*>(r0 + 16 * 100 + 96);
                }
            }
        }
        if constexpr (BN_IN) {
            if (ks < 3) {
                float4 S0 = *reinterpret_cast<const float4*>(&sa[g * 128 + kb]);
                float4 S1 = *reinterpret_cast<const float4*>(&sa[g * 128 + kb + 4]);
                float4 O0 = *reinterpret_cast<const float4*>(&sb[g * 128 + kb]);
                float4 O1 = *reinterpret_cast<const float4*>(&sb[g * 128 + kb + 4]);
                APP(a0,0,S0.x,O0.x) APP(a0,1,S0.y,O0.y) APP(a0,2,S0.z,O0.z) APP(a0,3,S0.w,O0.w)
                APP(a0,4,S1.x,O1.x) APP(a0,5,S1.y,O1.y) APP(a0,6,S1.z,O1.z) APP(a0,7,S1.w,O1.w)
                APP(a1,0,S0.x,O0.x) APP(a1,1,S0.y,O0.y) APP(a1,2,S0.z,O0.z) APP(a1,3,S0.w,O0.w)
                APP(a1,4,S1.x,O1.x) APP(a1,5,S1.y,O1.y) APP(a1,6,S1.z,O1.z) APP(a1,7,S1.w,O1.w)
            } else if (lg == 0) {       // tail channels 96..99 + bias slot 1.0
                float4 S0 = *reinterpret_cast<const float4*>(&sa[g * 128 + 96]);
                float4 O0 = *reinterpret_cast<const float4*>(&sb[g * 128 + 96]);
                APP(a0,0,S0.x,O0.x) APP(a0,1,S0.y,O0.y) APP(a0,2,S0.z,O0.z) APP(a0,3,S0.w,O0.w)
                APP(a1,0,S0.x,O0.x) APP(a1,1,S0.y,O0.y) APP(a1,2,S0.z,O0.z) APP(a1,3,S0.w,O0.w)
                a0[4] = (short)0x3F80; a1[4] = (short)0x3F80;
            }
        }
        bf16x8 av0 = __builtin_bit_cast(bf16x8, a0);
        bf16x8 av1 = __builtin_bit_cast(bf16x8, a1);
        #pragma unroll
        for (int nt = 0; nt < NT; ++nt) {
            s16x8 b = *reinterpret_cast<const s16x8*>(Uw + (size_t)((ks * NT + nt) * 64 + lane) * 8);
            bf16x8 bv = __builtin_bit_cast(bf16x8, b);
            if constexpr (IS_LAST) {
                acc[0][nt] = __builtin_amdgcn_mfma_f32_16x16x32_bf16(bv, av0, acc[0][nt], 0, 0, 0);
                acc[1][nt] = __builtin_amdgcn_mfma_f32_16x16x32_bf16(bv, av1, acc[1][nt], 0, 0, 0);
            } else {
                acc[0][nt] = __builtin_amdgcn_mfma_f32_16x16x32_bf16(av0, bv, acc[0][nt], 0, 0, 0);
                acc[1][nt] = __builtin_amdgcn_mfma_f32_16x16x32_bf16(av1, bv, acc[1][nt], 0, 0, 0);
            }
        }
    }
    #undef APP
    __syncthreads();                   // all W ds_reads done; U reusable

    // ---- epilogue: two 64-row phases through the bounce (aliases W) ----
    if constexpr (!IS_LAST) {
        unsigned short* LH = (unsigned short*)U;
        float rs1[NT] = {}, rs2[NT] = {};
        float bvn[NT];
        #pragma unroll
        for (int nt = 0; nt < NT; ++nt) {
            bvn[nt] = 0.f;
            if constexpr (HAS_BIAS) {
                int col = nt * 16 + lr;
                if (col < N_OUT) bvn[nt] = bias[g * N_OUT + col];
            }
        }
        #pragma unroll
        for (int p = 0; p < 2; ++p) {
            if ((wid >> 1) == p) {           // waves owning rows p*64..p*64+63
                #pragma unroll
                for (int nt = 0; nt < NT; ++nt) {
                    const int col = nt * 16 + lr;
                    const bool valid = col < N_OUT;
                    #pragma unroll
                    for (int mi = 0; mi < 2; ++mi) {
                        const int rloc = (wid & 1) * 32 + mi * 16 + (lg << 2);
                        #pragma unroll
                        for (int r = 0; r < 4; ++r) {
                            float v = acc[mi][nt][r] + bvn[nt];
                            short hb = cvt_bf16(v);
                            float vq = bfs2f(hb);
                            rs1[nt] += vq; rs2[nt] += vq * vq;
                            if (valid) LH[(rloc + r) * 104 + col] = (unsigned short)hb;
                        }
                    }
                }
            }
            __syncthreads();                 // half-tile parked
            #pragma unroll
            for (int i = 0; i < 7; ++i) {
                int e = t + i * 256;
                if (e < 1600) {
                    int row = e / 25;
                    int c4 = (e - row * 25) * 4;
                    ushort4 v = *reinterpret_cast<const ushort4*>(&LH[row * 104 + c4]);
                    *reinterpret_cast<ushort4*>(
                        Hout + ((size_t)g * B_SZ + m0 + p * 64 + row) * 100 + c4) = v;
                }
            }
            __syncthreads();                 // LH reusable
        }
        // deferred BN stats
        #pragma unroll
        for (int nt = 0; nt < NT; ++nt) {
            float s1 = rs1[nt], s2 = rs2[nt];
            s1 += __shfl_xor(s1, 16); s1 += __shfl_xor(s1, 32);
            s2 += __shfl_xor(s2, 16); s2 += __shfl_xor(s2, 32);
            const int col = nt * 16 + lr;
            if (col < N_OUT && lg == 0) {
                atomicAdd(&ls1[col], s1);
                atomicAdd(&ls2[col], s2);
            }
        }
        __syncthreads();
        if (t < N_OUT) {
            atomicAdd(&ssum[g * N_OUT + t], ls1[t]);
            atomicAdd(&ssq[g * N_OUT + t], ls2[t]);
        }
    } else {
        float* LP = (float*)U;
        #pragma unroll
        for (int p = 0; p < 2; ++p) {
            if ((wid >> 1) == p) {
                #pragma unroll
                for (int mi = 0; mi < 2; ++mi) {
                    const int bl = (wid & 1) * 32 + mi * 16 + lr;   // row in half
                    float dp = 0.f;
                    #pragma unroll
                    for (int nt = 0; nt < NT; ++nt) {
                        const int n0 = nt * 16 + (lg << 2);
                        f32x4 v = acc[mi][nt];
                        if (nt < 3) {
                            float2 w01 = *reinterpret_cast<const float2*>(&ow[g * N_OUT + n0]);
                            float2 w23 = *reinterpret_cast<const float2*>(&ow[g * N_OUT + n0 + 2]);
                            dp += v[0] * w01.x + v[1] * w01.y + v[2] * w23.x + v[3] * w23.y;
                            LP[bl * 52 + n0 + 0] = v[0]; LP[bl * 52 + n0 + 1] = v[1];
                            LP[bl * 52 + n0 + 2] = v[2]; LP[bl * 52 + n0 + 3] = v[3];
                        } else if (lg == 0) {  // n0 = 48: n=48,49 valid
                            float2 w01 = *reinterpret_cast<const float2*>(&ow[g * N_OUT + n0]);
                            dp += v[0] * w01.x + v[1] * w01.y;
                            LP[bl * 52 + n0 + 0] = v[0]; LP[bl * 52 + n0 + 1] = v[1];
                        }
                    }
                    dp += __shfl_xor(dp, 16); dp += __shfl_xor(dp, 32);
                    if (lg == 0) atomicAdd(&out_acc[m0 + p * 64 + bl], dp);
                }
            }
            __syncthreads();
            #pragma unroll
            for (int i = 0; i < 7; ++i) {
                int e = t + i * 256;
                if (e < 1600) {
                    int row = e / 25;
                    int c2 = e - row * 25;
                    float2 v = *reinterpret_cast<const float2*>(&LP[row * 52 + c2 * 2]);
                    *reinterpret_cast<float2*>(
                        &pred[(size_t)(m0 + p * 64 + row) * 5000 + g * N_OUT + c2 * 2]) = v;
                }
            }
            __syncthreads();
        }
    }
}

// BN finalize -> per-channel scale/offset (128-stride, identity pads).
__global__ __launch_bounds__(256) void k_bnfin(const float* __restrict__ ssum,
                                               const float* __restrict__ ssq,
                                               const float* __restrict__ gamma,
                                               const float* __restrict__ beta,
                                               float* __restrict__ sa,
                                               float* __restrict__ sb) {
    int c = blockIdx.x * 256 + threadIdx.x;
    if (c < G_SZ * 128) {
        int g = c >> 7, ch = c & 127;
        float s, o;
        if (ch < 100) {
            float mean = ssum[g * 100 + ch] * (1.f / 8192.f);
            float var = ssq[g * 100 + ch] * (1.f / 8192.f) - mean * mean;
            s = rsqrtf(var + 1e-5f) * gamma[g * 100 + ch];
            o = beta[g * 100 + ch] - mean * s;
        } else { s = 1.f; o = 0.f; }
        sa[c] = s; sb[c] = o;
    }
}

__global__ __launch_bounds__(256) void k_sig(const float* __restrict__ out_acc,
                                             const float* __restrict__ ob,
                                             float* __restrict__ out) {
    int b = blockIdx.x * 256 + threadIdx.x;
    if (b < B_SZ) {
        float v = ob[0] + out_acc[b];
        out[b] = 1.f / (1.f + expf(-v));
    }
}

extern "C" void kernel_launch(void* const* d_in, const int* in_sizes, int n_in,
                              void* d_out, int out_size, void* d_ws, size_t ws_size,
                              hipStream_t stream) {
    const float* x      = (const float*)d_in[0];
    const int*   uf     = (const int*)d_in[1];
    const float* w0     = (const float*)d_in[2];
    const float* b0     = (const float*)d_in[3];
    const float* w1     = (const float*)d_in[4];
    const float* b1     = (const float*)d_in[5];
    const float* w2     = (const float*)d_in[6];
    const float* b2     = (const float*)d_in[7];
    const float* gamma0 = (const float*)d_in[8];
    const float* beta0  = (const float*)d_in[9];
    const float* gamma1 = (const float*)d_in[10];
    const float* beta1  = (const float*)d_in[11];
    const float* ow     = (const float*)d_in[12];
    const float* ob     = (const float*)d_in[13];

    char* ws = (char*)d_ws;
    const size_t AG_BYTES = (size_t)G_SZ * B_SZ * 128 * 2;  // 209,715,200
    unsigned short* Ag = (unsigned short*)ws;
    unsigned short* h1 = Ag;   // row-major [100][8192][100] bf16; aliases Ag
    float* stat = (float*)(ws + AG_BYTES);
    float* sum0    = stat;            // 10000
    float* ssq0    = stat + 10000;
    float* sum1    = stat + 20000;
    float* ssq1    = stat + 30000;
    float* out_acc = stat + 40000;    // 8192  (zeroed region ends at 48192)
    float* sa0     = stat + 48192;    // 12800 each, fully written by bnfin
    float* sb0     = stat + 60992;
    float* sa1     = stat + 73792;
    float* sb1     = stat + 86592;    // ends 99392 floats = 397,568 B

    unsigned short* p0 = (unsigned short*)(ws + AG_BYTES + 397568);
    unsigned short* p1 = p0 + (size_t)179200 * 8;   // 2,867,200 B each
    unsigned short* p2 = p1 + (size_t)179200 * 8;   // p2: 1,638,400 B

    // h0 row-major in d_out's pred region (dead before dense2 writes pred).
    unsigned short* h0 = (unsigned short*)((float*)d_out + B_SZ);
    float* pred = (float*)d_out + B_SZ;
    float* sig  = (float*)d_out;

    hipMemsetAsync(stat, 0, 48192 * sizeof(float), stream);

    k_packW<<<1800, 256, 0, stream>>>(w0, w1, b1, w2, b2, p0, p1, p2);
    k_gather<<<B_SZ / 16, 256, 0, stream>>>(x, uf, Ag);

    // dense0: K=128 in, bias in epilogue
    k_dense<128, 100, 7, false, false, true><<<6400, 256, 0, stream>>>(
        Ag, p0, b0, nullptr, nullptr, h0, nullptr, sum0, ssq0, nullptr, nullptr);
    k_bnfin<<<50, 256, 0, stream>>>(sum0, ssq0, gamma0, beta0, sa0, sb0);

    // dense1: K=100 in (BN+fold), row-major out
    k_dense<100, 100, 7, true, false, false><<<6400, 256, 0, stream>>>(
        h0, p1, nullptr, sa0, sb0, h1, nullptr, sum1, ssq1, nullptr, nullptr);
    k_bnfin<<<50, 256, 0, stream>>>(sum1, ssq1, gamma1, beta1, sa1, sb1);

    // dense2: K=100 in (BN+fold), pred + dot out
    k_dense<100, 50, 4, true, true, false><<<6400, 256, 0, stream>>>(
        h1, p2, nullptr, sa1, sb1, nullptr, pred, nullptr, nullptr, ow, out_acc);

    k_sig<<<32, 256, 0, stream>>>(out_acc, ob, sig);
}

// Round 20
// 357.738 us; speedup vs baseline: 1.6572x; 1.0014x over previous
//
#include <hip/hip_runtime.h>

#define B_SZ 8192
#define IN_SZ 1024
#define G_SZ 100
#define F_SZ 128

using f32x4 = __attribute__((ext_vector_type(4))) float;
using s16x8 = __attribute__((ext_vector_type(8))) short;
typedef __bf16 bf16x8 __attribute__((ext_vector_type(8)));

__device__ __forceinline__ short cvt_bf16(float f) {      // HW RNE f32->bf16
    __bf16 h = (__bf16)f;
    return __builtin_bit_cast(short, h);
}
__device__ __forceinline__ float bfs2f(short s) {
    union { unsigned u; float f; } v; v.u = ((unsigned)(unsigned short)s) << 16;
    return v.f;
}

// async global->LDS, 16B per lane; LDS dest = uniform base + lane*16
#define GLDS(gp, lp) __builtin_amdgcn_global_load_lds( \
    (const __attribute__((address_space(1))) void*)(gp), \
    (__attribute__((address_space(3))) void*)(lp), 16, 0, 0)

// ---------------------------------------------------------------------------
// Gather: Ag[g][b][f] = bf16(x[b][uf[g*128+f]])
// ---------------------------------------------------------------------------
__global__ __launch_bounds__(256) void k_gather(const float* __restrict__ x,
                                                const int* __restrict__ uf,
                                                unsigned short* __restrict__ Ag) {
    __shared__ __align__(16) unsigned short xrow[16][1032];
    const int t = threadIdx.x;
    const int b0 = blockIdx.x * 16;
    #pragma unroll
    for (int i = 0; i < 16; ++i) {
        int c4 = t + i * 256;
        int r = c4 >> 8;
        int cc = (c4 & 255) << 2;
        float4 v = *reinterpret_cast<const float4*>(&x[(size_t)(b0 + r) * IN_SZ + cc]);
        ushort4 o;
        o.x = (unsigned short)cvt_bf16(v.x); o.y = (unsigned short)cvt_bf16(v.y);
        o.z = (unsigned short)cvt_bf16(v.z); o.w = (unsigned short)cvt_bf16(v.w);
        *reinterpret_cast<ushort4*>(&xrow[r][cc]) = o;
    }
    __syncthreads();
    for (int i = 0; i < 200; ++i) {
        int c = t + i * 256;
        int ch = c & 31; int r = (c >> 5) & 15; int g = c >> 9;
        int4 id = *reinterpret_cast<const int4*>(&uf[g * F_SZ + ch * 4]);
        ushort4 o;
        o.x = xrow[r][id.x]; o.y = xrow[r][id.y]; o.z = xrow[r][id.z]; o.w = xrow[r][id.w];
        *reinterpret_cast<ushort4*>(&Ag[(((size_t)g * B_SZ + b0 + r) << 7) + ch * 4]) = o;
    }
}

// ---------------------------------------------------------------------------
// Pre-pack W (+bias at k==K_SRC when FOLD) into MFMA fragment order.
// ---------------------------------------------------------------------------
template<int K_SRC, int N_OUT, int NT, bool FOLD>
__device__ __forceinline__ void pack_one(int e, const float* __restrict__ W,
                                         const float* __restrict__ bias,
                                         unsigned short* __restrict__ P) {
    constexpr int EPG = 4 * NT * 64;
    int g = e / EPG; int r = e - g * EPG;
    int lane = r & 63; int nt = (r >> 6) % NT; int ks = r / (64 * NT);
    int n = nt * 16 + (lane & 15); int kb = ks * 32 + (lane >> 4) * 8;
    s16x8 v;
    #pragma unroll
    for (int j = 0; j < 8; ++j) {
        int k = kb + j; float val = 0.f;
        if (n < N_OUT) {
            if (k < K_SRC) val = W[((size_t)g * K_SRC + k) * N_OUT + n];
            else if (FOLD && k == K_SRC) val = bias[g * N_OUT + n];
        }
        v[j] = cvt_bf16(val);
    }
    *reinterpret_cast<s16x8*>(&P[(size_t)e * 8]) = v;
}

__global__ __launch_bounds__(256) void k_packW(
    const float* __restrict__ w0,
    const float* __restrict__ w1, const float* __restrict__ b1,
    const float* __restrict__ w2, const float* __restrict__ b2,
    unsigned short* __restrict__ p0, unsigned short* __restrict__ p1,
    unsigned short* __restrict__ p2) {
    int id = blockIdx.x * 256 + threadIdx.x;           // 460800 total
    if (id < 179200)       pack_one<128, 100, 7, false>(id, w0, nullptr, p0);
    else if (id < 358400)  pack_one<100, 100, 7, true >(id - 179200, w1, b1, p1);
    else                   pack_one<100,  50, 4, true >(id - 358400, w2, b2, p2);
}

// ---------------------------------------------------------------------------
// Per-group dense, bf16 MFMA 16x16x32, ONE 128-row tile per block.
//  - W staged in LDS from packed table (zero-conflict ds_read_b128).
//  - A loaded per-ks (16 live regs), BN fused at load.
//  - MW (min waves/EU) per instantiation:
//      NT=7: acc 56 AGPR + ~60 arch = 116 unified -> MW=4 ONLY (5 spills,
//            proven R16/R17/R18).
//      NT=4: acc 32 + ~48 arch = ~80 unified <= 102 -> MW=5 fits w/ margin.
//  Canary: WRITE ~165MB / FETCH ~93MB = no spill (R19 verified @ MW=4:
//  dense=101.6us, dur = bytes/BW closes exactly).
// ---------------------------------------------------------------------------
template<int K_SRC, int N_OUT, int NT, bool BN_IN, bool IS_LAST, bool HAS_BIAS,
         int MW>
__global__ __launch_bounds__(256, MW) void k_dense(
    const unsigned short* __restrict__ Ain,   // [G][B][K_SRC] bf16 row-major
    const unsigned short* __restrict__ Wf,    // [G][4*NT*64][8] packed
    const float* __restrict__ bias,           // only when HAS_BIAS
    const float* __restrict__ sa, const float* __restrict__ sb, // [G*128]
    unsigned short* __restrict__ Hout,        // [G][B][N_OUT] bf16
    float* __restrict__ pred,                 // [B][5000] f32
    float* __restrict__ ssum, float* __restrict__ ssq, // [G*100]
    const float* __restrict__ ow, float* __restrict__ out_acc)
{
    constexpr int EPG = 4 * NT * 64;
    constexpr int WBYTES = EPG * 16;               // 28672 (NT=7) / 16384 (NT=4)
    constexpr int UBYTES = WBYTES > 13312 ? WBYTES : 13312;
    __shared__ __align__(16) unsigned char U[UBYTES];
    __shared__ float ls1[IS_LAST ? 1 : NT * 16];
    __shared__ float ls2[IS_LAST ? 1 : NT * 16];

    const int t = threadIdx.x;
    const int g = blockIdx.x >> 6;
    const int m0 = (blockIdx.x & 63) << 7;
    const int lane = t & 63, wid = t >> 6;
    const int lr = lane & 15, lg = lane >> 4;

    if constexpr (!IS_LAST) {
        if (t < NT * 16) { ls1[t] = 0.f; ls2[t] = 0.f; }
    }

    // ---- stage W into LDS (linear, async, L2-hot source) ----
    constexpr int NCH = WBYTES / 1024;             // 28 / 16
    const char* wsrc = (const char*)(Wf + (size_t)g * EPG * 8);
    #pragma unroll
    for (int j = 0; j < (NCH + 3) / 4; ++j) {
        int i = j * 4 + wid;                       // wave-uniform chunk index
        if (i < NCH) GLDS(wsrc + i * 1024 + lane * 16, U + i * 1024);
    }
    __syncthreads();                               // drains vmcnt: W resident

    const unsigned short* Uw = (const unsigned short*)U;
    const unsigned short* r0 = Ain + ((size_t)g * B_SZ + m0 + wid * 32 + lr) * K_SRC;

    #define APP(vv, idx, s, o) { float f_ = bfs2f(vv[idx]) * (s) + (o); \
                                 vv[idx] = cvt_bf16(fmaxf(f_, 0.f)); }

    // ---- MFMA loop: A per-ks from global (16 live regs), W from LDS ----
    f32x4 acc[2][NT] = {};
    #pragma unroll
    for (int ks = 0; ks < 4; ++ks) {
        s16x8 a0, a1;
        const int kb = ks * 32 + lg * 8;
        if constexpr (K_SRC == 128) {
            a0 = *reinterpret_cast<const s16x8*>(r0 + kb);
            a1 = *reinterpret_cast<const s16x8*>(r0 + 16 * 128 + kb);
        } else {  // K_SRC == 100
            if (ks < 3) {
                reinterpret_cast<short4*>(&a0)[0] = *reinterpret_cast<const short4*>(r0 + kb);
                reinterpret_cast<short4*>(&a0)[1] = *reinterpret_cast<const short4*>(r0 + kb + 4);
                reinterpret_cast<short4*>(&a1)[0] = *reinterpret_cast<const short4*>(r0 + 16 * 100 + kb);
                reinterpret_cast<short4*>(&a1)[1] = *reinterpret_cast<const short4*>(r0 + 16 * 100 + kb + 4);
            } else {
                a0 = s16x8{}; a1 = s16x8{};
                if (lg == 0) {
                    reinterpret_cast<short4*>(&a0)[0] = *reinterpret_cast<const short4*>(r0 + 96);
                    reinterpret_cast<short4*>(&a1)[0] = *reinterpret_cast<const short4*>(r0 + 16 * 100 + 96);
                }
            }
        }
        if constexpr (BN_IN) {
            if (ks < 3) {
                float4 S0 = *reinterpret_cast<const float4*>(&sa[g * 128 + kb]);
                float4 S1 = *reinterpret_cast<const float4*>(&sa[g * 128 + kb + 4]);
                float4 O0 = *reinterpret_cast<const float4*>(&sb[g * 128 + kb]);
                float4 O1 = *reinterpret_cast<const float4*>(&sb[g * 128 + kb + 4]);
                APP(a0,0,S0.x,O0.x) APP(a0,1,S0.y,O0.y) APP(a0,2,S0.z,O0.z) APP(a0,3,S0.w,O0.w)
                APP(a0,4,S1.x,O1.x) APP(a0,5,S1.y,O1.y) APP(a0,6,S1.z,O1.z) APP(a0,7,S1.w,O1.w)
                APP(a1,0,S0.x,O0.x) APP(a1,1,S0.y,O0.y) APP(a1,2,S0.z,O0.z) APP(a1,3,S0.w,O0.w)
                APP(a1,4,S1.x,O1.x) APP(a1,5,S1.y,O1.y) APP(a1,6,S1.z,O1.z) APP(a1,7,S1.w,O1.w)
            } else if (lg == 0) {       // tail channels 96..99 + bias slot 1.0
                float4 S0 = *reinterpret_cast<const float4*>(&sa[g * 128 + 96]);
                float4 O0 = *reinterpret_cast<const float4*>(&sb[g * 128 + 96]);
                APP(a0,0,S0.x,O0.x) APP(a0,1,S0.y,O0.y) APP(a0,2,S0.z,O0.z) APP(a0,3,S0.w,O0.w)
                APP(a1,0,S0.x,O0.x) APP(a1,1,S0.y,O0.y) APP(a1,2,S0.z,O0.z) APP(a1,3,S0.w,O0.w)
                a0[4] = (short)0x3F80; a1[4] = (short)0x3F80;
            }
        }
        bf16x8 av0 = __builtin_bit_cast(bf16x8, a0);
        bf16x8 av1 = __builtin_bit_cast(bf16x8, a1);
        #pragma unroll
        for (int nt = 0; nt < NT; ++nt) {
            s16x8 b = *reinterpret_cast<const s16x8*>(Uw + (size_t)((ks * NT + nt) * 64 + lane) * 8);
            bf16x8 bv = __builtin_bit_cast(bf16x8, b);
            if constexpr (IS_LAST) {
                acc[0][nt] = __builtin_amdgcn_mfma_f32_16x16x32_bf16(bv, av0, acc[0][nt], 0, 0, 0);
                acc[1][nt] = __builtin_amdgcn_mfma_f32_16x16x32_bf16(bv, av1, acc[1][nt], 0, 0, 0);
            } else {
                acc[0][nt] = __builtin_amdgcn_mfma_f32_16x16x32_bf16(av0, bv, acc[0][nt], 0, 0, 0);
                acc[1][nt] = __builtin_amdgcn_mfma_f32_16x16x32_bf16(av1, bv, acc[1][nt], 0, 0, 0);
            }
        }
    }
    #undef APP
    __syncthreads();                   // all W ds_reads done; U reusable

    // ---- epilogue: two 64-row phases through the bounce (aliases W) ----
    if constexpr (!IS_LAST) {
        unsigned short* LH = (unsigned short*)U;
        float rs1[NT] = {}, rs2[NT] = {};
        float bvn[NT];
        #pragma unroll
        for (int nt = 0; nt < NT; ++nt) {
            bvn[nt] = 0.f;
            if constexpr (HAS_BIAS) {
                int col = nt * 16 + lr;
                if (col < N_OUT) bvn[nt] = bias[g * N_OUT + col];
            }
        }
        #pragma unroll
        for (int p = 0; p < 2; ++p) {
            if ((wid >> 1) == p) {           // waves owning rows p*64..p*64+63
                #pragma unroll
                for (int nt = 0; nt < NT; ++nt) {
                    const int col = nt * 16 + lr;
                    const bool valid = col < N_OUT;
                    #pragma unroll
                    for (int mi = 0; mi < 2; ++mi) {
                        const int rloc = (wid & 1) * 32 + mi * 16 + (lg << 2);
                        #pragma unroll
                        for (int r = 0; r < 4; ++r) {
                            float v = acc[mi][nt][r] + bvn[nt];
                            short hb = cvt_bf16(v);
                            float vq = bfs2f(hb);
                            rs1[nt] += vq; rs2[nt] += vq * vq;
                            if (valid) LH[(rloc + r) * 104 + col] = (unsigned short)hb;
                        }
                    }
                }
            }
            __syncthreads();                 // half-tile parked
            #pragma unroll
            for (int i = 0; i < 7; ++i) {
                int e = t + i * 256;
                if (e < 1600) {
                    int row = e / 25;
                    int c4 = (e - row * 25) * 4;
                    ushort4 v = *reinterpret_cast<const ushort4*>(&LH[row * 104 + c4]);
                    *reinterpret_cast<ushort4*>(
                        Hout + ((size_t)g * B_SZ + m0 + p * 64 + row) * 100 + c4) = v;
                }
            }
            __syncthreads();                 // LH reusable
        }
        // deferred BN stats
        #pragma unroll
        for (int nt = 0; nt < NT; ++nt) {
            float s1 = rs1[nt], s2 = rs2[nt];
            s1 += __shfl_xor(s1, 16); s1 += __shfl_xor(s1, 32);
            s2 += __shfl_xor(s2, 16); s2 += __shfl_xor(s2, 32);
            const int col = nt * 16 + lr;
            if (col < N_OUT && lg == 0) {
                atomicAdd(&ls1[col], s1);
                atomicAdd(&ls2[col], s2);
            }
        }
        __syncthreads();
        if (t < N_OUT) {
            atomicAdd(&ssum[g * N_OUT + t], ls1[t]);
            atomicAdd(&ssq[g * N_OUT + t], ls2[t]);
        }
    } else {
        float* LP = (float*)U;
        #pragma unroll
        for (int p = 0; p < 2; ++p) {
            if ((wid >> 1) == p) {
                #pragma unroll
                for (int mi = 0; mi < 2; ++mi) {
                    const int bl = (wid & 1) * 32 + mi * 16 + lr;   // row in half
                    float dp = 0.f;
                    #pragma unroll
                    for (int nt = 0; nt < NT; ++nt) {
                        const int n0 = nt * 16 + (lg << 2);
                        f32x4 v = acc[mi][nt];
                        if (nt < 3) {
                            float2 w01 = *reinterpret_cast<const float2*>(&ow[g * N_OUT + n0]);
                            float2 w23 = *reinterpret_cast<const float2*>(&ow[g * N_OUT + n0 + 2]);
                            dp += v[0] * w01.x + v[1] * w01.y + v[2] * w23.x + v[3] * w23.y;
                            LP[bl * 52 + n0 + 0] = v[0]; LP[bl * 52 + n0 + 1] = v[1];
                            LP[bl * 52 + n0 + 2] = v[2]; LP[bl * 52 + n0 + 3] = v[3];
                        } else if (lg == 0) {  // n0 = 48: n=48,49 valid
                            float2 w01 = *reinterpret_cast<const float2*>(&ow[g * N_OUT + n0]);
                            dp += v[0] * w01.x + v[1] * w01.y;
                            LP[bl * 52 + n0 + 0] = v[0]; LP[bl * 52 + n0 + 1] = v[1];
                        }
                    }
                    dp += __shfl_xor(dp, 16); dp += __shfl_xor(dp, 32);
                    if (lg == 0) atomicAdd(&out_acc[m0 + p * 64 + bl], dp);
                }
            }
            __syncthreads();
            #pragma unroll
            for (int i = 0; i < 7; ++i) {
                int e = t + i * 256;
                if (e < 1600) {
                    int row = e / 25;
                    int c2 = e - row * 25;
                    float2 v = *reinterpret_cast<const float2*>(&LP[row * 52 + c2 * 2]);
                    *reinterpret_cast<float2*>(
                        &pred[(size_t)(m0 + p * 64 + row) * 5000 + g * N_OUT + c2 * 2]) = v;
                }
            }
            __syncthreads();
        }
    }
}

// BN finalize -> per-channel scale/offset (128-stride, identity pads).
__global__ __launch_bounds__(256) void k_bnfin(const float* __restrict__ ssum,
                                               const float* __restrict__ ssq,
                                               const float* __restrict__ gamma,
                                               const float* __restrict__ beta,
                                               float* __restrict__ sa,
                                               float* __restrict__ sb) {
    int c = blockIdx.x * 256 + threadIdx.x;
    if (c < G_SZ * 128) {
        int g = c >> 7, ch = c & 127;
        float s, o;
        if (ch < 100) {
            float mean = ssum[g * 100 + ch] * (1.f / 8192.f);
            float var = ssq[g * 100 + ch] * (1.f / 8192.f) - mean * mean;
            s = rsqrtf(var + 1e-5f) * gamma[g * 100 + ch];
            o = beta[g * 100 + ch] - mean * s;
        } else { s = 1.f; o = 0.f; }
        sa[c] = s; sb[c] = o;
    }
}

__global__ __launch_bounds__(256) void k_sig(const float* __restrict__ out_acc,
                                             const float* __restrict__ ob,
                                             float* __restrict__ out) {
    int b = blockIdx.x * 256 + threadIdx.x;
    if (b < B_SZ) {
        float v = ob[0] + out_acc[b];
        out[b] = 1.f / (1.f + expf(-v));
    }
}

extern "C" void kernel_launch(void* const* d_in, const int* in_sizes, int n_in,
                              void* d_out, int out_size, void* d_ws, size_t ws_size,
                              hipStream_t stream) {
    const float* x      = (const float*)d_in[0];
    const int*   uf     = (const int*)d_in[1];
    const float* w0     = (const float*)d_in[2];
    const float* b0     = (const float*)d_in[3];
    const float* w1     = (const float*)d_in[4];
    const float* b1     = (const float*)d_in[5];
    const float* w2     = (const float*)d_in[6];
    const float* b2     = (const float*)d_in[7];
    const float* gamma0 = (const float*)d_in[8];
    const float* beta0  = (const float*)d_in[9];
    const float* gamma1 = (const float*)d_in[10];
    const float* beta1  = (const float*)d_in[11];
    const float* ow     = (const float*)d_in[12];
    const float* ob     = (const float*)d_in[13];

    char* ws = (char*)d_ws;
    const size_t AG_BYTES = (size_t)G_SZ * B_SZ * 128 * 2;  // 209,715,200
    unsigned short* Ag = (unsigned short*)ws;
    unsigned short* h1 = Ag;   // row-major [100][8192][100] bf16; aliases Ag
    float* stat = (float*)(ws + AG_BYTES);
    float* sum0    = stat;            // 10000
    float* ssq0    = stat + 10000;
    float* sum1    = stat + 20000;
    float* ssq1    = stat + 30000;
    float* out_acc = stat + 40000;    // 8192  (zeroed region ends at 48192)
    float* sa0     = stat + 48192;    // 12800 each, fully written by bnfin
    float* sb0     = stat + 60992;
    float* sa1     = stat + 73792;
    float* sb1     = stat + 86592;    // ends 99392 floats = 397,568 B

    unsigned short* p0 = (unsigned short*)(ws + AG_BYTES + 397568);
    unsigned short* p1 = p0 + (size_t)179200 * 8;   // 2,867,200 B each
    unsigned short* p2 = p1 + (size_t)179200 * 8;   // p2: 1,638,400 B

    // h0 row-major in d_out's pred region (dead before dense2 writes pred).
    unsigned short* h0 = (unsigned short*)((float*)d_out + B_SZ);
    float* pred = (float*)d_out + B_SZ;
    float* sig  = (float*)d_out;

    hipMemsetAsync(stat, 0, 48192 * sizeof(float), stream);

    k_packW<<<1800, 256, 0, stream>>>(w0, w1, b1, w2, b2, p0, p1, p2);
    k_gather<<<B_SZ / 16, 256, 0, stream>>>(x, uf, Ag);

    // dense0: K=128 in, bias in epilogue (NT=7 -> MW=4)
    k_dense<128, 100, 7, false, false, true, 4><<<6400, 256, 0, stream>>>(
        Ag, p0, b0, nullptr, nullptr, h0, nullptr, sum0, ssq0, nullptr, nullptr);
    k_bnfin<<<50, 256, 0, stream>>>(sum0, ssq0, gamma0, beta0, sa0, sb0);

    // dense1: K=100 in (BN+fold), row-major out (NT=7 -> MW=4)
    k_dense<100, 100, 7, true, false, false, 4><<<6400, 256, 0, stream>>>(
        h0, p1, nullptr, sa0, sb0, h1, nullptr, sum1, ssq1, nullptr, nullptr);
    k_bnfin<<<50, 256, 0, stream>>>(sum1, ssq1, gamma1, beta1, sa1, sb1);

    // dense2: K=100 in (BN+fold), pred + dot out (NT=4, acc=32 -> MW=5 fits)
    k_dense<100, 50, 4, true, true, false, 5><<<6400, 256, 0, stream>>>(
        h1, p2, nullptr, sa1, sb1, nullptr, pred, nullptr, nullptr, ow, out_acc);

    k_sig<<<32, 256, 0, stream>>>(out_acc, ob, sig);
}